// Round 16
// baseline (281.399 us; speedup 1.0000x reference)
//
#include <hip/hip_runtime.h>

#define NB 2048
#define NS 1024
#define NL 32

typedef short bf16x8 __attribute__((ext_vector_type(8)));
typedef float f32x16 __attribute__((ext_vector_type(16)));
union FragU { unsigned u[4]; bf16x8 v; };

static __device__ __forceinline__ float fexp2(float x) {
#if __has_builtin(__builtin_amdgcn_exp2f)
  return __builtin_amdgcn_exp2f(x);
#else
  float r; asm("v_exp_f32 %0, %1" : "=v"(r) : "v"(x)); return r;
#endif
}
static __device__ __forceinline__ float flog2(float x) {
#if __has_builtin(__builtin_amdgcn_logf)
  return __builtin_amdgcn_logf(x);
#else
  float r; asm("v_log_f32 %0, %1" : "=v"(r) : "v"(x)); return r;
#endif
}

template<int K>
static __device__ __forceinline__ int roti(int x) {
  if constexpr (K == 0) return x;
  else return __builtin_amdgcn_update_dpp(0, x, 0x120 | K, 0xf, 0xf, true); // row_ror:K
}
template<int K>
static __device__ __forceinline__ float rotf(float x) {
  return __int_as_float(roti<K>(__float_as_int(x)));
}

// in-place permlane32 swap with s_nop hazard guards (R10-validated pattern)
static __device__ __forceinline__ void plswap32_pair(unsigned &x, unsigned &y) {
  asm volatile("s_nop 1\n\tv_permlane32_swap_b32 %0, %1\n\ts_nop 1"
               : "+v"(x), "+v"(y));
}
static __device__ __forceinline__ float plswap16_sum(float part) {
  float x, y;
  asm volatile("v_mov_b32 %0, %2\n\tv_mov_b32 %1, %2\n\ts_nop 1\n\t"
               "v_permlane16_swap_b32 %0, %1\n\ts_nop 1"
               : "=&v"(x), "=&v"(y) : "v"(part));
  return x + y;
}
static __device__ __forceinline__ float plswap32_sum(float part) {
  float x, y;
  asm volatile("v_mov_b32 %0, %2\n\tv_mov_b32 %1, %2\n\ts_nop 1\n\t"
               "v_permlane32_swap_b32 %0, %1\n\ts_nop 1"
               : "=&v"(x), "=&v"(y) : "v"(part));
  return x + y;
}
static __device__ __forceinline__ float plswap32_max(float part) {
  float x, y;
  asm volatile("v_mov_b32 %0, %2\n\tv_mov_b32 %1, %2\n\ts_nop 1\n\t"
               "v_permlane32_swap_b32 %0, %1\n\ts_nop 1"
               : "=&v"(x), "=&v"(y) : "v"(part));
  return fmaxf(x, y);
}
static __device__ __forceinline__ int plswap16_partner(int lane) {
  float x, y;
  asm volatile("v_mov_b32 %0, %2\n\tv_mov_b32 %1, %2\n\ts_nop 1\n\t"
               "v_permlane16_swap_b32 %0, %1\n\ts_nop 1"
               : "=&v"(x), "=&v"(y) : "v"((float)lane));
  return (int)(x + y) - lane;
}

// pack two f32 -> bf16x2 (src0 -> lo)
static __device__ __forceinline__ unsigned cvtpk(float a, float b) {
  unsigned r;
  asm("v_cvt_pk_bf16_f32 %0, %1, %2" : "=v"(r) : "v"(a), "v"(b));
  return r;
}
static __device__ __forceinline__ float bf2f(unsigned short u) {
  return __int_as_float(((int)u) << 16);
}

// 16-term rotate/FMA tree: sum_k rot_k(p) * E[k]
static __device__ __forceinline__ float tree16(float p, const float* E) {
  float a0 = p * E[0];
  float a1 = rotf<1>(p) * E[1];
  float a2 = rotf<2>(p) * E[2];
  float a3 = rotf<3>(p) * E[3];
  a0 = fmaf(rotf<4>(p),  E[4],  a0);
  a1 = fmaf(rotf<5>(p),  E[5],  a1);
  a2 = fmaf(rotf<6>(p),  E[6],  a2);
  a3 = fmaf(rotf<7>(p),  E[7],  a3);
  a0 = fmaf(rotf<8>(p),  E[8],  a0);
  a1 = fmaf(rotf<9>(p),  E[9],  a1);
  a2 = fmaf(rotf<10>(p), E[10], a2);
  a3 = fmaf(rotf<11>(p), E[11], a3);
  a0 = fmaf(rotf<12>(p), E[12], a0);
  a1 = fmaf(rotf<13>(p), E[13], a1);
  a2 = fmaf(rotf<14>(p), E[14], a2);
  a3 = fmaf(rotf<15>(p), E[15], a3);
  return (a0 + a1) + (a2 + a3);
}

__global__ void zero_out_k(float* out) {
  if (threadIdx.x < 2) out[threadIdx.x] = 0.0f;
}

// 8 waves/block. Phase 1: wave w builds chunk-w operator matrix via MFMA with
// PER-COLUMN max renorm (pins every column max to [1,2) -> acc <= 2^20 always,
// inf/NaN structurally impossible; per-column log scales X[c] tracked and
// re-applied in phase 2). Phase 2: wave 0 chains a0 through the 8 matrices.
__global__ __launch_bounds__(512)
void crf_fwd(const float* __restrict__ scores, const float* __restrict__ trans,
             const int* __restrict__ lens, const int* __restrict__ tags,
             float* __restrict__ out)
{
  constexpr float LOG2E = 1.4426950408889634f;
  constexpr float LN2   = 0.6931471805599453f;
  __shared__ float Tld[NL * NL];
  __shared__ alignas(16) unsigned short Mb[8][NL * NL]; // Mb[i][k] = M[i][k]*2^-X[i]
  __shared__ float Xls[8][NL];

  const int b    = blockIdx.x;
  const int tid  = threadIdx.x;
  const int w    = tid >> 6;
  const int lane = tid & 63;
  const int len  = lens[b];
  const int col  = lane & 31;
  const int half = lane >> 5;
  const float* sbf = scores + (size_t)b * (NS * NL);

  for (int k = tid; k < NL * NL; k += 512) Tld[k] = trans[k] * LOG2E;

  // runtime probe of permlane32_swap direction
  unsigned px = half ? 200u : 100u, py = half ? 400u : 300u;
  plswap32_pair(px, py);
  const bool dirC1 = (__builtin_amdgcn_readfirstlane(px) == 100u);

  __syncthreads();

  // ---------------- phase 1: chunk operator matrices ----------------
  const int t0 = 1 + (w << 7);
  int v = len - t0; v = v < 0 ? 0 : (v > 128 ? 128 : v);

  if (v == 0) {
    unsigned* mw = (unsigned*)&Mb[w][0];
    #pragma unroll
    for (int q = 0; q < 8; ++q) mw[lane + 64 * q] = 0u;
    asm volatile("s_waitcnt lgkmcnt(0)" ::: "memory");
    if (lane < 32) { Mb[w][lane * NL + lane] = 0x3F80; Xls[w][lane] = 0.0f; }
  } else {
    // A[r][k] = G^T[r][k] = E[k][r]*w[r]; lane row r = col
    float EAb1[8], EAb2[8];
    #pragma unroll
    for (int p = 0; p < 8; ++p) {
      EAb1[p] = fexp2(Tld[(8 * half + p) * NL + col]);
      EAb2[p] = fexp2(Tld[(16 + 8 * half + p) * NL + col]);
    }
    f32x16 acc;
    #pragma unroll
    for (int i = 0; i < 16; ++i) {
      const int row = (i & 3) + 8 * (i >> 2) + 4 * half;
      acc[i] = (row == col) ? 1.0f : 0.0f;   // S = I (col-max = 1, X = 0)
    }
    float Xw = 0.0f;

#define LDROW(T) sbf[(size_t)(((T) > len - 1) ? (len - 1) : (T)) * NL + col]
    float er0 = LDROW(t0 + 0), er1 = LDROW(t0 + 1), er2 = LDROW(t0 + 2), er3 = LDROW(t0 + 3);
    float er4 = LDROW(t0 + 4), er5 = LDROW(t0 + 5), er6 = LDROW(t0 + 6), er7 = LDROW(t0 + 7);

#define MSTEP(EQ) do { \
    const float ws_ = fexp2((EQ) * LOG2E); \
    FragU a1_, a2_, b1_, b2_; \
    _Pragma("unroll") \
    for (int p_ = 0; p_ < 4; ++p_) { \
      a1_.u[p_] = cvtpk(EAb1[2 * p_] * ws_, EAb1[2 * p_ + 1] * ws_); \
      a2_.u[p_] = cvtpk(EAb2[2 * p_] * ws_, EAb2[2 * p_ + 1] * ws_); \
    } \
    unsigned pk0_ = cvtpk(acc[0],  acc[1]),  pk1_ = cvtpk(acc[2],  acc[3]); \
    unsigned pk2_ = cvtpk(acc[4],  acc[5]),  pk3_ = cvtpk(acc[6],  acc[7]); \
    unsigned pk4_ = cvtpk(acc[8],  acc[9]),  pk5_ = cvtpk(acc[10], acc[11]); \
    unsigned pk6_ = cvtpk(acc[12], acc[13]), pk7_ = cvtpk(acc[14], acc[15]); \
    if (dirC1) { \
      plswap32_pair(pk0_, pk2_); b1_.u[0] = pk0_; b1_.u[2] = pk2_; \
      plswap32_pair(pk1_, pk3_); b1_.u[1] = pk1_; b1_.u[3] = pk3_; \
      plswap32_pair(pk4_, pk6_); b2_.u[0] = pk4_; b2_.u[2] = pk6_; \
      plswap32_pair(pk5_, pk7_); b2_.u[1] = pk5_; b2_.u[3] = pk7_; \
    } else { \
      plswap32_pair(pk2_, pk0_); b1_.u[2] = pk2_; b1_.u[0] = pk0_; \
      plswap32_pair(pk3_, pk1_); b1_.u[3] = pk3_; b1_.u[1] = pk1_; \
      plswap32_pair(pk6_, pk4_); b2_.u[2] = pk6_; b2_.u[0] = pk4_; \
      plswap32_pair(pk7_, pk5_); b2_.u[3] = pk7_; b2_.u[1] = pk5_; \
    } \
    f32x16 z_; \
    _Pragma("unroll") \
    for (int i_ = 0; i_ < 16; ++i_) z_[i_] = 0.0f; \
    z_  = __builtin_amdgcn_mfma_f32_32x32x16_bf16(a1_.v, b1_.v, z_, 0, 0, 0); \
    acc = __builtin_amdgcn_mfma_f32_32x32x16_bf16(a2_.v, b2_.v, z_, 0, 0, 0); \
    /* per-column renorm: pin col-max to [1,2) */ \
    float mx_ = fmaxf(fmaxf(fmaxf(acc[0], acc[1]), fmaxf(acc[2], acc[3])), \
                      fmaxf(fmaxf(acc[4], acc[5]), fmaxf(acc[6], acc[7]))); \
    mx_ = fmaxf(mx_, fmaxf(fmaxf(fmaxf(acc[8], acc[9]), fmaxf(acc[10], acc[11])), \
                           fmaxf(fmaxf(acc[12], acc[13]), fmaxf(acc[14], acc[15])))); \
    mx_ = plswap32_max(mx_); \
    const int ex_ = (__float_as_int(mx_) >> 23) - 127; \
    const float rs_ = __int_as_float((127 - ex_) << 23); \
    _Pragma("unroll") \
    for (int i_ = 0; i_ < 16; ++i_) acc[i_] *= rs_; \
    Xw += (float)ex_; \
  } while (0)

    int sg = 0;
    while (sg + 8 <= v) {
      MSTEP(er0); er0 = LDROW(t0 + sg + 8);
      MSTEP(er1); er1 = LDROW(t0 + sg + 9);
      MSTEP(er2); er2 = LDROW(t0 + sg + 10);
      MSTEP(er3); er3 = LDROW(t0 + sg + 11);
      MSTEP(er4); er4 = LDROW(t0 + sg + 12);
      MSTEP(er5); er5 = LDROW(t0 + sg + 13);
      MSTEP(er6); er6 = LDROW(t0 + sg + 14);
      MSTEP(er7); er7 = LDROW(t0 + sg + 15);
      sg += 8;
    }
    if (sg + 0 < v) MSTEP(er0);
    if (sg + 1 < v) MSTEP(er1);
    if (sg + 2 < v) MSTEP(er2);
    if (sg + 3 < v) MSTEP(er3);
    if (sg + 4 < v) MSTEP(er4);
    if (sg + 5 < v) MSTEP(er5);
    if (sg + 6 < v) MSTEP(er6);
    if (sg + 7 < v) MSTEP(er7);

    // store scaled S^T: Mb[col][row] = S[row][col] (= M[col][row]*2^-X[col])
    {
      unsigned* mw32 = (unsigned*)&Mb[w][0];
      #pragma unroll
      for (int j = 0; j < 8; ++j) {
        const int row0 = (2 * j & 3) + 8 * (2 * j >> 2) + 4 * half;
        mw32[(col * NL + row0) >> 1] = cvtpk(acc[2 * j], acc[2 * j + 1]);
      }
    }
    if (lane < 32) Xls[w][col] = Xw;
#undef MSTEP
#undef LDROW
  }

  __syncthreads();

  // ---------------- phase 2 ----------------
  if (w == 0) {
    const int r16 = lane >> 4, c16 = lane & 15;
    const int labA = c16 + ((r16 & 1) << 4);
    const int p16 = plswap16_partner(lane);
    const bool plOK = ((p16 & 15) == c16) && ((((p16 >> 4) ^ r16) & 1) == 1);
    const int pmax = (lane > p16) ? lane : p16;
    const int labB = plOK ? (c16 + ((pmax >= 48) ? 16 : 0))
                          : (c16 + (((r16 >> 1) & 1) << 4));
#define COMB16(S) (plOK ? plswap16_sum(S) : ((S) + __shfl_xor((S), 16)))

    float a0 = Tld[31 * NL + labA] + LOG2E * sbf[labA];
    const float ls0 = __int_as_float(__builtin_amdgcn_readfirstlane(__float_as_int(a0)));
    float u = fexp2(a0 - ls0);
    float lstot = ls0;

    for (int c = 0; c < 8; ++c) {
      const bool phA = !(c & 1);
      const int held = phA ? labA : labB;
      const int outl = phA ? labB : labA;
      // re-apply chunk's per-column scales: u[held] *= 2^(X[held] - X0)
      const float dX = Xls[c][held];
      const float X0 = __int_as_float(__builtin_amdgcn_readfirstlane(__float_as_int(dX)));
      u *= fexp2(fminf(dX - X0, 120.0f));
      lstot += X0;
      {  // renorm u (pin u[label0], strictly positive)
        const int eb = __builtin_amdgcn_readfirstlane(__float_as_int(u));
        const int ex = (eb >> 23) - 127;
        lstot += (float)ex;
        u *= __int_as_float((127 - ex) << 23);
      }
      float Ec[16];
#define LDE(K) Ec[K] = bf2f(Mb[c][roti<K>(held) * NL + outl]);
      LDE(0)  LDE(1)  LDE(2)  LDE(3)  LDE(4)  LDE(5)  LDE(6)  LDE(7)
      LDE(8)  LDE(9)  LDE(10) LDE(11) LDE(12) LDE(13) LDE(14) LDE(15)
#undef LDE
      const float s16 = tree16(u, Ec);
      u = phA ? COMB16(s16) : plswap32_sum(s16);
      {  // renorm
        const int eb = __builtin_amdgcn_readfirstlane(__float_as_int(u));
        const int ex = (eb >> 23) - 127;
        lstot += (float)ex;
        u *= __int_as_float((127 - ex) << 23);
      }
    }
    // 8 chunks (even) -> layout A. Each label duplicated 2x -> subtract 1
    float vend = u * fexp2(Tld[labA * NL + 30]);
    float ssum = vend;
    #pragma unroll
    for (int ww = 32; ww; ww >>= 1) ssum += __shfl_xor(ssum, ww);
    if (lane == 0) atomicAdd(out + 0, LN2 * (lstot + flog2(ssum) - 1.0f));
#undef COMB16
  } else if (w == 1) {
    // labeled score
    const int* tb = tags + (size_t)b * NS;
    float lab = 0.0f;
    if (lane == 0) {
      const int tg0 = tb[0];
      lab += Tld[31 * NL + tg0] + LOG2E * sbf[tg0];
      const int tgl = tb[len - 1];
      lab += Tld[tgl * NL + 30];
    }
    for (int t2 = 1 + lane; t2 < len; t2 += 64) {
      const int tp = tb[t2 - 1];
      const int tg = tb[t2];
      lab += Tld[tp * NL + tg] + LOG2E * sbf[(size_t)t2 * NL + tg];
    }
    #pragma unroll
    for (int ww = 32; ww; ww >>= 1) lab += __shfl_xor(lab, ww);
    if (lane == 0) atomicAdd(out + 1, LN2 * lab);
  }
}

extern "C" void kernel_launch(void* const* d_in, const int* in_sizes, int n_in,
                              void* d_out, int out_size, void* d_ws, size_t ws_size,
                              hipStream_t stream) {
  const float* scores = (const float*)d_in[0];
  const float* trans  = (const float*)d_in[1];
  const int*   lens   = (const int*)d_in[2];
  const int*   tags   = (const int*)d_in[3];
  float* out = (float*)d_out;

  zero_out_k<<<1, 64, 0, stream>>>(out);
  crf_fwd<<<NB, 512, 0, stream>>>(scores, trans, lens, tags, out);
}

// Round 18
// 255.678 us; speedup vs baseline: 1.1006x; 1.1006x over previous
//
#include <hip/hip_runtime.h>

#define NB 2048
#define NS 1024
#define NL 32

typedef short bf16x8 __attribute__((ext_vector_type(8)));
typedef float f32x16 __attribute__((ext_vector_type(16)));
union FragU { unsigned u[4]; bf16x8 v; };

static __device__ __forceinline__ float fexp2(float x) {
#if __has_builtin(__builtin_amdgcn_exp2f)
  return __builtin_amdgcn_exp2f(x);
#else
  float r; asm("v_exp_f32 %0, %1" : "=v"(r) : "v"(x)); return r;
#endif
}
static __device__ __forceinline__ float flog2(float x) {
#if __has_builtin(__builtin_amdgcn_logf)
  return __builtin_amdgcn_logf(x);
#else
  float r; asm("v_log_f32 %0, %1" : "=v"(r) : "v"(x)); return r;
#endif
}

template<int K>
static __device__ __forceinline__ int roti(int x) {
  if constexpr (K == 0) return x;
  else return __builtin_amdgcn_update_dpp(0, x, 0x120 | K, 0xf, 0xf, true); // row_ror:K
}
template<int K>
static __device__ __forceinline__ float rotf(float x) {
  return __int_as_float(roti<K>(__float_as_int(x)));
}

// in-place permlane32 swap with s_nop hazard guards (R10-validated pattern)
static __device__ __forceinline__ void plswap32_pair(unsigned &x, unsigned &y) {
  asm volatile("s_nop 1\n\tv_permlane32_swap_b32 %0, %1\n\ts_nop 1"
               : "+v"(x), "+v"(y));
}
static __device__ __forceinline__ float plswap16_sum(float part) {
  float x, y;
  asm volatile("v_mov_b32 %0, %2\n\tv_mov_b32 %1, %2\n\ts_nop 1\n\t"
               "v_permlane16_swap_b32 %0, %1\n\ts_nop 1"
               : "=&v"(x), "=&v"(y) : "v"(part));
  return x + y;
}
static __device__ __forceinline__ float plswap32_sum(float part) {
  float x, y;
  asm volatile("v_mov_b32 %0, %2\n\tv_mov_b32 %1, %2\n\ts_nop 1\n\t"
               "v_permlane32_swap_b32 %0, %1\n\ts_nop 1"
               : "=&v"(x), "=&v"(y) : "v"(part));
  return x + y;
}
static __device__ __forceinline__ float plswap32_max(float part) {
  float x, y;
  asm volatile("v_mov_b32 %0, %2\n\tv_mov_b32 %1, %2\n\ts_nop 1\n\t"
               "v_permlane32_swap_b32 %0, %1\n\ts_nop 1"
               : "=&v"(x), "=&v"(y) : "v"(part));
  return fmaxf(x, y);
}
static __device__ __forceinline__ int plswap16_partner(int lane) {
  float x, y;
  asm volatile("v_mov_b32 %0, %2\n\tv_mov_b32 %1, %2\n\ts_nop 1\n\t"
               "v_permlane16_swap_b32 %0, %1\n\ts_nop 1"
               : "=&v"(x), "=&v"(y) : "v"((float)lane));
  return (int)(x + y) - lane;
}

// pack two f32 -> bf16x2 (src0 -> lo)
static __device__ __forceinline__ unsigned cvtpk(float a, float b) {
  unsigned r;
  asm("v_cvt_pk_bf16_f32 %0, %1, %2" : "=v"(r) : "v"(a), "v"(b));
  return r;
}
static __device__ __forceinline__ float bf2f(unsigned short u) {
  return __int_as_float(((int)u) << 16);
}

// 16-term rotate/FMA tree: sum_k rot_k(p) * E[k]
static __device__ __forceinline__ float tree16(float p, const float* E) {
  float a0 = p * E[0];
  float a1 = rotf<1>(p) * E[1];
  float a2 = rotf<2>(p) * E[2];
  float a3 = rotf<3>(p) * E[3];
  a0 = fmaf(rotf<4>(p),  E[4],  a0);
  a1 = fmaf(rotf<5>(p),  E[5],  a1);
  a2 = fmaf(rotf<6>(p),  E[6],  a2);
  a3 = fmaf(rotf<7>(p),  E[7],  a3);
  a0 = fmaf(rotf<8>(p),  E[8],  a0);
  a1 = fmaf(rotf<9>(p),  E[9],  a1);
  a2 = fmaf(rotf<10>(p), E[10], a2);
  a3 = fmaf(rotf<11>(p), E[11], a3);
  a0 = fmaf(rotf<12>(p), E[12], a0);
  a1 = fmaf(rotf<13>(p), E[13], a1);
  a2 = fmaf(rotf<14>(p), E[14], a2);
  a3 = fmaf(rotf<15>(p), E[15], a3);
  return (a0 + a1) + (a2 + a3);
}

__global__ void zero_out_k(float* out) {
  if (threadIdx.x < 2) out[threadIdx.x] = 0.0f;
}

// 8 waves/block. Phase 1: wave w builds chunk-w operator matrix via MFMA with
// PER-COLUMN max renorm every step (R16-validated bit-exact). ONLY change vs
// R16: chunk size is dynamic cs = ceil((len-1)/8) so ALL 8 waves are active
// for every batch (R16's fixed-128 chunks idled ~half the waves -> 45% occ).
// Phase 2: wave 0 chains a0 through the 8 matrices (R16-validated).
__global__ __launch_bounds__(512)
void crf_fwd(const float* __restrict__ scores, const float* __restrict__ trans,
             const int* __restrict__ lens, const int* __restrict__ tags,
             float* __restrict__ out)
{
  constexpr float LOG2E = 1.4426950408889634f;
  constexpr float LN2   = 0.6931471805599453f;
  __shared__ float Tld[NL * NL];
  __shared__ alignas(16) unsigned short Mb[8][NL * NL]; // Mb[i][k] = M[i][k]*2^-X[i]
  __shared__ float Xls[8][NL];

  const int b    = blockIdx.x;
  const int tid  = threadIdx.x;
  const int w    = tid >> 6;
  const int lane = tid & 63;
  const int len  = lens[b];
  const int col  = lane & 31;
  const int half = lane >> 5;
  const float* sbf = scores + (size_t)b * (NS * NL);

  for (int k = tid; k < NL * NL; k += 512) Tld[k] = trans[k] * LOG2E;

  // runtime probe of permlane32_swap direction
  unsigned px = half ? 200u : 100u, py = half ? 400u : 300u;
  plswap32_pair(px, py);
  const bool dirC1 = (__builtin_amdgcn_readfirstlane(px) == 100u);

  __syncthreads();

  // ---------------- phase 1: chunk operator matrices ----------------
  const int cs = (len - 1 + 7) >> 3;          // dynamic chunk size (0 if len==1)
  const int t0 = 1 + w * cs;
  int v = len - t0; v = v < 0 ? 0 : (v > cs ? cs : v);

  if (v == 0) {
    unsigned* mw = (unsigned*)&Mb[w][0];
    #pragma unroll
    for (int q = 0; q < 8; ++q) mw[lane + 64 * q] = 0u;
    asm volatile("s_waitcnt lgkmcnt(0)" ::: "memory");
    if (lane < 32) { Mb[w][lane * NL + lane] = 0x3F80; Xls[w][lane] = 0.0f; }
  } else {
    // A[r][k] = G^T[r][k] = E[k][r]*w[r]; lane row r = col
    float EAb1[8], EAb2[8];
    #pragma unroll
    for (int p = 0; p < 8; ++p) {
      EAb1[p] = fexp2(Tld[(8 * half + p) * NL + col]);
      EAb2[p] = fexp2(Tld[(16 + 8 * half + p) * NL + col]);
    }
    f32x16 acc;
    #pragma unroll
    for (int i = 0; i < 16; ++i) {
      const int row = (i & 3) + 8 * (i >> 2) + 4 * half;
      acc[i] = (row == col) ? 1.0f : 0.0f;   // S = I (col-max = 1, X = 0)
    }
    float Xw = 0.0f;

#define LDROW(T) sbf[(size_t)(((T) > len - 1) ? (len - 1) : (T)) * NL + col]
    float er0 = LDROW(t0 + 0), er1 = LDROW(t0 + 1), er2 = LDROW(t0 + 2), er3 = LDROW(t0 + 3);
    float er4 = LDROW(t0 + 4), er5 = LDROW(t0 + 5), er6 = LDROW(t0 + 6), er7 = LDROW(t0 + 7);

#define MSTEP(EQ) do { \
    const float ws_ = fexp2((EQ) * LOG2E); \
    FragU a1_, a2_, b1_, b2_; \
    _Pragma("unroll") \
    for (int p_ = 0; p_ < 4; ++p_) { \
      a1_.u[p_] = cvtpk(EAb1[2 * p_] * ws_, EAb1[2 * p_ + 1] * ws_); \
      a2_.u[p_] = cvtpk(EAb2[2 * p_] * ws_, EAb2[2 * p_ + 1] * ws_); \
    } \
    unsigned pk0_ = cvtpk(acc[0],  acc[1]),  pk1_ = cvtpk(acc[2],  acc[3]); \
    unsigned pk2_ = cvtpk(acc[4],  acc[5]),  pk3_ = cvtpk(acc[6],  acc[7]); \
    unsigned pk4_ = cvtpk(acc[8],  acc[9]),  pk5_ = cvtpk(acc[10], acc[11]); \
    unsigned pk6_ = cvtpk(acc[12], acc[13]), pk7_ = cvtpk(acc[14], acc[15]); \
    if (dirC1) { \
      plswap32_pair(pk0_, pk2_); b1_.u[0] = pk0_; b1_.u[2] = pk2_; \
      plswap32_pair(pk1_, pk3_); b1_.u[1] = pk1_; b1_.u[3] = pk3_; \
      plswap32_pair(pk4_, pk6_); b2_.u[0] = pk4_; b2_.u[2] = pk6_; \
      plswap32_pair(pk5_, pk7_); b2_.u[1] = pk5_; b2_.u[3] = pk7_; \
    } else { \
      plswap32_pair(pk2_, pk0_); b1_.u[2] = pk2_; b1_.u[0] = pk0_; \
      plswap32_pair(pk3_, pk1_); b1_.u[3] = pk3_; b1_.u[1] = pk1_; \
      plswap32_pair(pk6_, pk4_); b2_.u[2] = pk6_; b2_.u[0] = pk4_; \
      plswap32_pair(pk7_, pk5_); b2_.u[3] = pk7_; b2_.u[1] = pk5_; \
    } \
    f32x16 z_; \
    _Pragma("unroll") \
    for (int i_ = 0; i_ < 16; ++i_) z_[i_] = 0.0f; \
    z_  = __builtin_amdgcn_mfma_f32_32x32x16_bf16(a1_.v, b1_.v, z_, 0, 0, 0); \
    acc = __builtin_amdgcn_mfma_f32_32x32x16_bf16(a2_.v, b2_.v, z_, 0, 0, 0); \
    /* per-column renorm: pin col-max to [1,2) */ \
    float mx_ = fmaxf(fmaxf(fmaxf(acc[0], acc[1]), fmaxf(acc[2], acc[3])), \
                      fmaxf(fmaxf(acc[4], acc[5]), fmaxf(acc[6], acc[7]))); \
    mx_ = fmaxf(mx_, fmaxf(fmaxf(fmaxf(acc[8], acc[9]), fmaxf(acc[10], acc[11])), \
                           fmaxf(fmaxf(acc[12], acc[13]), fmaxf(acc[14], acc[15])))); \
    mx_ = plswap32_max(mx_); \
    const int ex_ = (__float_as_int(mx_) >> 23) - 127; \
    const float rs_ = __int_as_float((127 - ex_) << 23); \
    _Pragma("unroll") \
    for (int i_ = 0; i_ < 16; ++i_) acc[i_] *= rs_; \
    Xw += (float)ex_; \
  } while (0)

    int sg = 0;
    while (sg + 8 <= v) {
      MSTEP(er0); er0 = LDROW(t0 + sg + 8);
      MSTEP(er1); er1 = LDROW(t0 + sg + 9);
      MSTEP(er2); er2 = LDROW(t0 + sg + 10);
      MSTEP(er3); er3 = LDROW(t0 + sg + 11);
      MSTEP(er4); er4 = LDROW(t0 + sg + 12);
      MSTEP(er5); er5 = LDROW(t0 + sg + 13);
      MSTEP(er6); er6 = LDROW(t0 + sg + 14);
      MSTEP(er7); er7 = LDROW(t0 + sg + 15);
      sg += 8;
    }
    if (sg + 0 < v) MSTEP(er0);
    if (sg + 1 < v) MSTEP(er1);
    if (sg + 2 < v) MSTEP(er2);
    if (sg + 3 < v) MSTEP(er3);
    if (sg + 4 < v) MSTEP(er4);
    if (sg + 5 < v) MSTEP(er5);
    if (sg + 6 < v) MSTEP(er6);
    if (sg + 7 < v) MSTEP(er7);

    // store scaled S: Mb[col][row] (= S[row][col], col-scaled)
    {
      unsigned* mw32 = (unsigned*)&Mb[w][0];
      #pragma unroll
      for (int j = 0; j < 8; ++j) {
        const int row0 = (2 * j & 3) + 8 * (2 * j >> 2) + 4 * half;
        mw32[(col * NL + row0) >> 1] = cvtpk(acc[2 * j], acc[2 * j + 1]);
      }
    }
    if (lane < 32) Xls[w][col] = Xw;
#undef MSTEP
#undef LDROW
  }

  __syncthreads();

  // ---------------- phase 2 ----------------
  if (w == 0) {
    const int r16 = lane >> 4, c16 = lane & 15;
    const int labA = c16 + ((r16 & 1) << 4);
    const int p16 = plswap16_partner(lane);
    const bool plOK = ((p16 & 15) == c16) && ((((p16 >> 4) ^ r16) & 1) == 1);
    const int pmax = (lane > p16) ? lane : p16;
    const int labB = plOK ? (c16 + ((pmax >= 48) ? 16 : 0))
                          : (c16 + (((r16 >> 1) & 1) << 4));
#define COMB16(S) (plOK ? plswap16_sum(S) : ((S) + __shfl_xor((S), 16)))

    float a0 = Tld[31 * NL + labA] + LOG2E * sbf[labA];
    const float ls0 = __int_as_float(__builtin_amdgcn_readfirstlane(__float_as_int(a0)));
    float u = fexp2(a0 - ls0);
    float lstot = ls0;

    for (int c = 0; c < 8; ++c) {
      const bool phA = !(c & 1);
      const int held = phA ? labA : labB;
      const int outl = phA ? labB : labA;
      // re-apply chunk's per-column scales: u[held] *= 2^(X[held] - X0)
      const float dX = Xls[c][held];
      const float X0 = __int_as_float(__builtin_amdgcn_readfirstlane(__float_as_int(dX)));
      u *= fexp2(fminf(dX - X0, 120.0f));
      lstot += X0;
      {  // renorm u (pin u[label0], strictly positive)
        const int eb = __builtin_amdgcn_readfirstlane(__float_as_int(u));
        const int ex = (eb >> 23) - 127;
        lstot += (float)ex;
        u *= __int_as_float((127 - ex) << 23);
      }
      float Ec[16];
#define LDE(K) Ec[K] = bf2f(Mb[c][roti<K>(held) * NL + outl]);
      LDE(0)  LDE(1)  LDE(2)  LDE(3)  LDE(4)  LDE(5)  LDE(6)  LDE(7)
      LDE(8)  LDE(9)  LDE(10) LDE(11) LDE(12) LDE(13) LDE(14) LDE(15)
#undef LDE
      const float s16 = tree16(u, Ec);
      u = phA ? COMB16(s16) : plswap32_sum(s16);
      {  // renorm
        const int eb = __builtin_amdgcn_readfirstlane(__float_as_int(u));
        const int ex = (eb >> 23) - 127;
        lstot += (float)ex;
        u *= __int_as_float((127 - ex) << 23);
      }
    }
    // 8 chunks (even) -> layout A. Each label duplicated 2x -> subtract 1
    float vend = u * fexp2(Tld[labA * NL + 30]);
    float ssum = vend;
    #pragma unroll
    for (int ww = 32; ww; ww >>= 1) ssum += __shfl_xor(ssum, ww);
    if (lane == 0) atomicAdd(out + 0, LN2 * (lstot + flog2(ssum) - 1.0f));
#undef COMB16
  } else if (w == 1) {
    // labeled score
    const int* tb = tags + (size_t)b * NS;
    float lab = 0.0f;
    if (lane == 0) {
      const int tg0 = tb[0];
      lab += Tld[31 * NL + tg0] + LOG2E * sbf[tg0];
      const int tgl = tb[len - 1];
      lab += Tld[tgl * NL + 30];
    }
    for (int t2 = 1 + lane; t2 < len; t2 += 64) {
      const int tp = tb[t2 - 1];
      const int tg = tb[t2];
      lab += Tld[tp * NL + tg] + LOG2E * sbf[(size_t)t2 * NL + tg];
    }
    #pragma unroll
    for (int ww = 32; ww; ww >>= 1) lab += __shfl_xor(lab, ww);
    if (lane == 0) atomicAdd(out + 1, LN2 * lab);
  }
}

extern "C" void kernel_launch(void* const* d_in, const int* in_sizes, int n_in,
                              void* d_out, int out_size, void* d_ws, size_t ws_size,
                              hipStream_t stream) {
  const float* scores = (const float*)d_in[0];
  const float* trans  = (const float*)d_in[1];
  const int*   lens   = (const int*)d_in[2];
  const int*   tags   = (const int*)d_in[3];
  float* out = (float*)d_out;

  zero_out_k<<<1, 64, 0, stream>>>(out);
  crf_fwd<<<NB, 512, 0, stream>>>(scores, trans, lens, tags, out);
}

// Round 21
// 147.560 us; speedup vs baseline: 1.9070x; 1.7327x over previous
//
#include <hip/hip_runtime.h>

#define NB 2048
#define NS 1024
#define NL 32

static __device__ __forceinline__ float fexp2(float x) {
#if __has_builtin(__builtin_amdgcn_exp2f)
  return __builtin_amdgcn_exp2f(x);
#else
  float r; asm("v_exp_f32 %0, %1" : "=v"(r) : "v"(x)); return r;
#endif
}
static __device__ __forceinline__ float flog2(float x) {
#if __has_builtin(__builtin_amdgcn_logf)
  return __builtin_amdgcn_logf(x);
#else
  float r; asm("v_log_f32 %0, %1" : "=v"(r) : "v"(x)); return r;
#endif
}

template<int K>
static __device__ __forceinline__ int roti(int x) {
  if constexpr (K == 0) return x;
  else return __builtin_amdgcn_update_dpp(0, x, 0x120 | K, 0xf, 0xf, true); // row_ror:K
}
template<int K>
static __device__ __forceinline__ float rotf(float x) {
  return __int_as_float(roti<K>(__float_as_int(x)));
}

// part + part[pair(lane)] via permlane swaps with s_nop hazard guards (R10-validated).
static __device__ __forceinline__ float plswap16_sum(float part) {
  float x, y;
  asm volatile("v_mov_b32 %0, %2\n\t"
               "v_mov_b32 %1, %2\n\t"
               "s_nop 1\n\t"
               "v_permlane16_swap_b32 %0, %1\n\t"
               "s_nop 1"
               : "=&v"(x), "=&v"(y) : "v"(part));
  return x + y;
}
static __device__ __forceinline__ float plswap32_sum(float part) {
  float x, y;
  asm volatile("v_mov_b32 %0, %2\n\t"
               "v_mov_b32 %1, %2\n\t"
               "s_nop 1\n\t"
               "v_permlane32_swap_b32 %0, %1\n\t"
               "s_nop 1"
               : "=&v"(x), "=&v"(y) : "v"(part));
  return x + y;
}
static __device__ __forceinline__ int plswap16_partner(int lane) {
  int x, y;
  asm volatile("v_mov_b32 %0, %2\n\t"
               "v_mov_b32 %1, %2\n\t"
               "s_nop 1\n\t"
               "v_permlane16_swap_b32 %0, %1\n\t"
               "s_nop 1"
               : "=&v"(x), "=&v"(y) : "v"(lane));
  return x + y - lane;
}

// 16-term rotate/FMA tree: sum_k rot_k(p) * E[k]
static __device__ __forceinline__ float tree16(float p, const float* E) {
  float a0 = p * E[0];
  float a1 = rotf<1>(p) * E[1];
  float a2 = rotf<2>(p) * E[2];
  float a3 = rotf<3>(p) * E[3];
  a0 = fmaf(rotf<4>(p),  E[4],  a0);
  a1 = fmaf(rotf<5>(p),  E[5],  a1);
  a2 = fmaf(rotf<6>(p),  E[6],  a2);
  a3 = fmaf(rotf<7>(p),  E[7],  a3);
  a0 = fmaf(rotf<8>(p),  E[8],  a0);
  a1 = fmaf(rotf<9>(p),  E[9],  a1);
  a2 = fmaf(rotf<10>(p), E[10], a2);
  a3 = fmaf(rotf<11>(p), E[11], a3);
  a0 = fmaf(rotf<12>(p), E[12], a0);
  a1 = fmaf(rotf<13>(p), E[13], a1);
  a2 = fmaf(rotf<14>(p), E[14], a2);
  a3 = fmaf(rotf<15>(p), E[15], a3);
  return (a0 + a1) + (a2 + a3);
}

__global__ void zero_out_k(float* out) {
  if (threadIdx.x < 2) out[threadIdx.x] = 0.0f;
}

// 2 waves/block: wave0 = forward alpha chain, wave1 = backward beta chain.
// Emits gathered DIRECTLY from global (one 128B line/step) into an 8-deep
// register pipeline — no LDS on the recurrence path except the combine swaps.
__global__ __launch_bounds__(128, 2)
void crf_fwd(const float* __restrict__ scores, const float* __restrict__ trans,
             const int* __restrict__ lens, const int* __restrict__ tags,
             float* __restrict__ out)
{
  constexpr float LOG2E = 1.4426950408889634f;
  constexpr float LN2   = 0.6931471805599453f;
  __shared__ float Tld[NL * NL];
  __shared__ float slotm[64];

  const int b    = blockIdx.x;
  const int tid  = threadIdx.x;
  const int wid  = tid >> 6;
  const int lane = tid & 63;
  const int len  = lens[b];
  const int m    = len >> 1;            // forward: m steps -> alpha_m
  const int nB   = len - 1 - m;         // backward: nB steps -> beta_m
  const int r = lane >> 4, c = lane & 15;
  const int labA = c + ((r & 1) << 4);

  const int p16 = plswap16_partner(lane);
  const bool plOK = ((p16 & 15) == c) && ((((p16 >> 4) ^ r) & 1) == 1);
  const int pmax = (lane > p16) ? lane : p16;
  const int labB = plOK ? (c + ((pmax >= 48) ? 16 : 0))
                        : (c + (((r >> 1) & 1) << 4));

  const float* sbf = scores + (size_t)b * (NS * NL);

  for (int k2 = tid; k2 < NL * NL; k2 += 128) Tld[k2] = trans[k2] * LOG2E;
  __syncthreads();

#define COMB16(S) (plOK ? plswap16_sum(S) : ((S) + __shfl_xor((S), 16)))
// clamped global emit gather: row in [0, len-1]; one 128B line per load
#define LDROW(DST, ROW, LAB) do { \
    int r_ = (ROW); r_ = r_ < 0 ? 0 : r_; r_ = r_ > len - 1 ? len - 1 : r_; \
    DST = sbf[(size_t)r_ * NL + (LAB)]; \
  } while (0)

  float u, ls;
  bool endB = false;

  if (wid == 0) {
    // ---------------- forward ----------------
    float EA[16], EB[16];
#define CFA(K) EA[K] = fexp2(Tld[roti<K>(labA) * NL + labB]);
#define CFB(K) EB[K] = fexp2(Tld[roti<K>(labB) * NL + labA]);
    CFA(0)  CFA(1)  CFA(2)  CFA(3)  CFA(4)  CFA(5)  CFA(6)  CFA(7)
    CFA(8)  CFA(9)  CFA(10) CFA(11) CFA(12) CFA(13) CFA(14) CFA(15)
    CFB(0)  CFB(1)  CFB(2)  CFB(3)  CFB(4)  CFB(5)  CFB(6)  CFB(7)
    CFB(8)  CFB(9)  CFB(10) CFB(11) CFB(12) CFB(13) CFB(14) CFB(15)
#undef CFA
#undef CFB
    float a0 = Tld[31 * NL + labA] + LOG2E * sbf[labA];
    ls = __int_as_float(__builtin_amdgcn_readfirstlane(__float_as_int(a0)));
    u = fexp2(a0 - ls);

#define RENORM do { \
    const int eb_ = __builtin_amdgcn_readfirstlane(__float_as_int(u)); \
    const int ex_ = (eb_ >> 23) - 127; \
    ls += (float)ex_; \
    u *= __int_as_float((127 - ex_) << 23); \
  } while (0)

    // 8-deep emit pipeline: P = steps t..t+3, Q = t+4..t+7
    float P0, P1, P2, P3, Q0, Q1, Q2, Q3;
    int t = 1;
    LDROW(P0, 1, labB); LDROW(P1, 2, labA); LDROW(P2, 3, labB); LDROW(P3, 4, labA);
    LDROW(Q0, 5, labB); LDROW(Q1, 6, labA); LDROW(Q2, 7, labB); LDROW(Q3, 8, labA);

#define FBODY(B0, B1, B2, B3) do { \
    RENORM; \
    const float w0 = fexp2(B0 * LOG2E); \
    const float w1 = fexp2(B1 * LOG2E); \
    const float w2 = fexp2(B2 * LOG2E); \
    const float w3 = fexp2(B3 * LOG2E); \
    LDROW(B0, t + 8,  labB); LDROW(B1, t + 9,  labA); \
    LDROW(B2, t + 10, labB); LDROW(B3, t + 11, labA); \
    u = COMB16(tree16(u, EA)) * w0; \
    u = plswap32_sum(tree16(u, EB)) * w1; \
    u = COMB16(tree16(u, EA)) * w2; \
    u = plswap32_sum(tree16(u, EB)) * w3; \
  } while (0)

    while (t + 7 <= m) {
      FBODY(P0, P1, P2, P3); t += 4;
      FBODY(Q0, Q1, Q2, Q3); t += 4;
    }
    if (t + 3 <= m) { FBODY(P0, P1, P2, P3); t += 4; }
    // drain (<=3 steps), direct loads
    while (t <= m) {
      if ((t & 3) == 1) RENORM;
      if (t & 1) {          // A-step
        float e; LDROW(e, t, labB);
        u = COMB16(tree16(u, EA)) * fexp2(e * LOG2E);
        endB = true;
      } else {              // B-step
        float e; LDROW(e, t, labA);
        u = plswap32_sum(tree16(u, EB)) * fexp2(e * LOG2E);
        endB = false;
      }
      t++;
    }
#undef FBODY
  } else {
    // ---------------- backward ----------------
    float EA[16], EB[16];
#define CBA(K) EA[K] = fexp2(Tld[labB * NL + roti<K>(labA)]);
#define CBB(K) EB[K] = fexp2(Tld[labA * NL + roti<K>(labB)]);
    CBA(0)  CBA(1)  CBA(2)  CBA(3)  CBA(4)  CBA(5)  CBA(6)  CBA(7)
    CBA(8)  CBA(9)  CBA(10) CBA(11) CBA(12) CBA(13) CBA(14) CBA(15)
    CBB(0)  CBB(1)  CBB(2)  CBB(3)  CBB(4)  CBB(5)  CBB(6)  CBB(7)
    CBB(8)  CBB(9)  CBB(10) CBB(11) CBB(12) CBB(13) CBB(14) CBB(15)
#undef CBA
#undef CBB
    float a0 = Tld[labA * NL + 30];
    ls = __int_as_float(__builtin_amdgcn_readfirstlane(__float_as_int(a0)));
    u = fexp2(a0 - ls);

#define RENORMB do { \
    const int eb_ = __builtin_amdgcn_readfirstlane(__float_as_int(u)); \
    const int ex_ = (eb_ >> 23) - 127; \
    ls += (float)ex_; \
    u *= __int_as_float((127 - ex_) << 23); \
  } while (0)

    float P0, P1, P2, P3, Q0, Q1, Q2, Q3;
    int k = 0;
    LDROW(P0, len - 1, labA); LDROW(P1, len - 2, labB);
    LDROW(P2, len - 3, labA); LDROW(P3, len - 4, labB);
    LDROW(Q0, len - 5, labA); LDROW(Q1, len - 6, labB);
    LDROW(Q2, len - 7, labA); LDROW(Q3, len - 8, labB);

#define BBODY(B0, B1, B2, B3) do { \
    RENORMB; \
    const float w0 = fexp2(B0 * LOG2E); \
    const float w1 = fexp2(B1 * LOG2E); \
    const float w2 = fexp2(B2 * LOG2E); \
    const float w3 = fexp2(B3 * LOG2E); \
    LDROW(B0, len - 1 - k - 8,  labA); LDROW(B1, len - 2 - k - 8,  labB); \
    LDROW(B2, len - 3 - k - 8,  labA); LDROW(B3, len - 4 - k - 8,  labB); \
    u = COMB16(tree16(u * w0, EA)); \
    u = plswap32_sum(tree16(u * w1, EB)); \
    u = COMB16(tree16(u * w2, EA)); \
    u = plswap32_sum(tree16(u * w3, EB)); \
  } while (0)

    while (k + 7 < nB) {
      BBODY(P0, P1, P2, P3); k += 4;
      BBODY(Q0, Q1, Q2, Q3); k += 4;
    }
    if (k + 3 < nB) { BBODY(P0, P1, P2, P3); k += 4; }
    while (k < nB) {
      if ((k & 3) == 0) RENORMB;
      if (!(k & 1)) {       // A-step
        float e; LDROW(e, len - 1 - k, labA);
        u = COMB16(tree16(u * fexp2(e * LOG2E), EA));
        endB = true;
      } else {              // B-step
        float e; LDROW(e, len - 1 - k, labB);
        u = plswap32_sum(tree16(u * fexp2(e * LOG2E), EB));
        endB = false;
      }
      k++;
    }
#undef BBODY
#undef RENORMB
  }

  // -------- junction: Z = ln2 * LSE2_j(alphalog[j] + betalog[j]) --------
  slotm[wid * 32 + (endB ? labB : labA)] = ls + flog2(u);
  __syncthreads();

  if (wid == 0) {
    float v2 = (lane < 32) ? (slotm[lane] + slotm[32 + lane]) : -3.0e38f;
    float mm = v2;
    #pragma unroll
    for (int w = 32; w; w >>= 1) mm = fmaxf(mm, __shfl_xor(mm, w));
    float ssum = fexp2(v2 - mm);
    #pragma unroll
    for (int w = 32; w; w >>= 1) ssum += __shfl_xor(ssum, w);
    if (lane == 0) atomicAdd(out + 0, LN2 * (mm + flog2(ssum)));

    // -------- labeled score --------
    const int* tb = tags + (size_t)b * NS;
    float lab = 0.0f;
    if (lane == 0) {
      const int tg0 = tb[0];
      lab += Tld[31 * NL + tg0] + LOG2E * sbf[tg0];
      const int tgl = tb[len - 1];
      lab += Tld[tgl * NL + 30];
    }
    for (int t2 = 1 + lane; t2 < len; t2 += 64) {
      const int tp = tb[t2 - 1];
      const int tg = tb[t2];
      lab += Tld[tp * NL + tg] + LOG2E * sbf[(size_t)t2 * NL + tg];
    }
    #pragma unroll
    for (int w = 32; w; w >>= 1) lab += __shfl_xor(lab, w);
    if (lane == 0) atomicAdd(out + 1, LN2 * lab);
  }
#undef COMB16
#undef LDROW
#undef RENORM
}

extern "C" void kernel_launch(void* const* d_in, const int* in_sizes, int n_in,
                              void* d_out, int out_size, void* d_ws, size_t ws_size,
                              hipStream_t stream) {
  const float* scores = (const float*)d_in[0];
  const float* trans  = (const float*)d_in[1];
  const int*   lens   = (const int*)d_in[2];
  const int*   tags   = (const int*)d_in[3];
  float* out = (float*)d_out;

  zero_out_k<<<1, 64, 0, stream>>>(out);
  crf_fwd<<<NB, 128, 0, stream>>>(scores, trans, lens, tags, out);
}

// Round 22
// 129.541 us; speedup vs baseline: 2.1723x; 1.1391x over previous
//
#include <hip/hip_runtime.h>

#define NB 2048
#define NS 1024
#define NL 32

static __device__ __forceinline__ float fexp2(float x) {
#if __has_builtin(__builtin_amdgcn_exp2f)
  return __builtin_amdgcn_exp2f(x);
#else
  float r; asm("v_exp_f32 %0, %1" : "=v"(r) : "v"(x)); return r;
#endif
}
static __device__ __forceinline__ float flog2(float x) {
#if __has_builtin(__builtin_amdgcn_logf)
  return __builtin_amdgcn_logf(x);
#else
  float r; asm("v_log_f32 %0, %1" : "=v"(r) : "v"(x)); return r;
#endif
}

template<int K>
static __device__ __forceinline__ int roti(int x) {
  if constexpr (K == 0) return x;
  else return __builtin_amdgcn_update_dpp(0, x, 0x120 | K, 0xf, 0xf, true); // row_ror:K
}
template<int K>
static __device__ __forceinline__ float rotf(float x) {
  return __int_as_float(roti<K>(__float_as_int(x)));
}

// part + part[pair(lane)] via permlane swaps with s_nop hazard guards (R10-validated).
static __device__ __forceinline__ float plswap16_sum(float part) {
  float x, y;
  asm volatile("v_mov_b32 %0, %2\n\t"
               "v_mov_b32 %1, %2\n\t"
               "s_nop 1\n\t"
               "v_permlane16_swap_b32 %0, %1\n\t"
               "s_nop 1"
               : "=&v"(x), "=&v"(y) : "v"(part));
  return x + y;
}
static __device__ __forceinline__ float plswap32_sum(float part) {
  float x, y;
  asm volatile("v_mov_b32 %0, %2\n\t"
               "v_mov_b32 %1, %2\n\t"
               "s_nop 1\n\t"
               "v_permlane32_swap_b32 %0, %1\n\t"
               "s_nop 1"
               : "=&v"(x), "=&v"(y) : "v"(part));
  return x + y;
}
static __device__ __forceinline__ int plswap16_partner(int lane) {
  int x, y;
  asm volatile("v_mov_b32 %0, %2\n\t"
               "v_mov_b32 %1, %2\n\t"
               "s_nop 1\n\t"
               "v_permlane16_swap_b32 %0, %1\n\t"
               "s_nop 1"
               : "=&v"(x), "=&v"(y) : "v"(lane));
  return x + y - lane;
}

// 16-term rotate/FMA tree: sum_k rot_k(p) * E[k]
static __device__ __forceinline__ float tree16(float p, const float* E) {
  float a0 = p * E[0];
  float a1 = rotf<1>(p) * E[1];
  float a2 = rotf<2>(p) * E[2];
  float a3 = rotf<3>(p) * E[3];
  a0 = fmaf(rotf<4>(p),  E[4],  a0);
  a1 = fmaf(rotf<5>(p),  E[5],  a1);
  a2 = fmaf(rotf<6>(p),  E[6],  a2);
  a3 = fmaf(rotf<7>(p),  E[7],  a3);
  a0 = fmaf(rotf<8>(p),  E[8],  a0);
  a1 = fmaf(rotf<9>(p),  E[9],  a1);
  a2 = fmaf(rotf<10>(p), E[10], a2);
  a3 = fmaf(rotf<11>(p), E[11], a3);
  a0 = fmaf(rotf<12>(p), E[12], a0);
  a1 = fmaf(rotf<13>(p), E[13], a1);
  a2 = fmaf(rotf<14>(p), E[14], a2);
  a3 = fmaf(rotf<15>(p), E[15], a3);
  return (a0 + a1) + (a2 + a3);
}

__global__ void zero_out_k(float* out) {
  if (threadIdx.x < 2) out[threadIdx.x] = 0.0f;
}

// counting sort by descending length: perm[pos] = batch index, longest first.
// One 1024-thread block; key = 1024 - len in [0, 1023].
__global__ __launch_bounds__(1024)
void sort_perm_k(const int* __restrict__ lens, int* __restrict__ perm) {
  __shared__ int h0[1024], h1[1024];
  const int tid = threadIdx.x;
  h0[tid] = 0;
  __syncthreads();
  for (int i = tid; i < NB; i += 1024) atomicAdd(&h0[1024 - lens[i]], 1);
  __syncthreads();
  const int cnt = h0[tid];
  // inclusive scan (Hillis-Steele, ping-pong)
  int* src = h0; int* dst = h1;
  for (int off = 1; off < 1024; off <<= 1) {
    dst[tid] = src[tid] + ((tid >= off) ? src[tid - off] : 0);
    __syncthreads();
    int* tmp = src; src = dst; dst = tmp;
  }
  const int excl = src[tid] - cnt;   // exclusive offset for this key
  __syncthreads();
  dst[tid] = excl;                   // dst = cursor array
  __syncthreads();
  for (int i = tid; i < NB; i += 1024) {
    const int key = 1024 - lens[i];
    const int pos = atomicAdd(&dst[key], 1);
    perm[pos] = i;
  }
}

// 2 waves/block: wave0 = forward alpha chain, wave1 = backward beta chain.
// Emits gathered DIRECTLY from global into an 8-deep register pipeline.
// Blocks process batches in DESCENDING length order via perm (LPT scheduling:
// kills the late-phase straggler where a long chain runs alone).
__global__ __launch_bounds__(128, 2)
void crf_fwd(const float* __restrict__ scores, const float* __restrict__ trans,
             const int* __restrict__ lens, const int* __restrict__ tags,
             const int* __restrict__ perm, float* __restrict__ out)
{
  constexpr float LOG2E = 1.4426950408889634f;
  constexpr float LN2   = 0.6931471805599453f;
  __shared__ float Tld[NL * NL];
  __shared__ float slotm[64];

  const int b    = perm ? perm[blockIdx.x] : blockIdx.x;
  const int tid  = threadIdx.x;
  const int wid  = tid >> 6;
  const int lane = tid & 63;
  const int len  = lens[b];
  const int m    = len >> 1;            // forward: m steps -> alpha_m
  const int nB   = len - 1 - m;         // backward: nB steps -> beta_m
  const int r = lane >> 4, c = lane & 15;
  const int labA = c + ((r & 1) << 4);

  const int p16 = plswap16_partner(lane);
  const bool plOK = ((p16 & 15) == c) && ((((p16 >> 4) ^ r) & 1) == 1);
  const int pmax = (lane > p16) ? lane : p16;
  const int labB = plOK ? (c + ((pmax >= 48) ? 16 : 0))
                        : (c + (((r >> 1) & 1) << 4));

  const float* sbf = scores + (size_t)b * (NS * NL);

  for (int k2 = tid; k2 < NL * NL; k2 += 128) Tld[k2] = trans[k2] * LOG2E;
  __syncthreads();

#define COMB16(S) (plOK ? plswap16_sum(S) : ((S) + __shfl_xor((S), 16)))
// clamped global emit gather: row in [0, len-1]; one 128B line per load
#define LDROW(DST, ROW, LAB) do { \
    int r_ = (ROW); r_ = r_ < 0 ? 0 : r_; r_ = r_ > len - 1 ? len - 1 : r_; \
    DST = sbf[(size_t)r_ * NL + (LAB)]; \
  } while (0)

  float u, ls;
  bool endB = false;

  if (wid == 0) {
    // ---------------- forward ----------------
    float EA[16], EB[16];
#define CFA(K) EA[K] = fexp2(Tld[roti<K>(labA) * NL + labB]);
#define CFB(K) EB[K] = fexp2(Tld[roti<K>(labB) * NL + labA]);
    CFA(0)  CFA(1)  CFA(2)  CFA(3)  CFA(4)  CFA(5)  CFA(6)  CFA(7)
    CFA(8)  CFA(9)  CFA(10) CFA(11) CFA(12) CFA(13) CFA(14) CFA(15)
    CFB(0)  CFB(1)  CFB(2)  CFB(3)  CFB(4)  CFB(5)  CFB(6)  CFB(7)
    CFB(8)  CFB(9)  CFB(10) CFB(11) CFB(12) CFB(13) CFB(14) CFB(15)
#undef CFA
#undef CFB
    float a0 = Tld[31 * NL + labA] + LOG2E * sbf[labA];
    ls = __int_as_float(__builtin_amdgcn_readfirstlane(__float_as_int(a0)));
    u = fexp2(a0 - ls);

#define RENORM do { \
    const int eb_ = __builtin_amdgcn_readfirstlane(__float_as_int(u)); \
    const int ex_ = (eb_ >> 23) - 127; \
    ls += (float)ex_; \
    u *= __int_as_float((127 - ex_) << 23); \
  } while (0)

    // 8-deep emit pipeline: P = steps t..t+3, Q = t+4..t+7
    float P0, P1, P2, P3, Q0, Q1, Q2, Q3;
    int t = 1;
    LDROW(P0, 1, labB); LDROW(P1, 2, labA); LDROW(P2, 3, labB); LDROW(P3, 4, labA);
    LDROW(Q0, 5, labB); LDROW(Q1, 6, labA); LDROW(Q2, 7, labB); LDROW(Q3, 8, labA);

#define FBODY(B0, B1, B2, B3) do { \
    RENORM; \
    const float w0 = fexp2(B0 * LOG2E); \
    const float w1 = fexp2(B1 * LOG2E); \
    const float w2 = fexp2(B2 * LOG2E); \
    const float w3 = fexp2(B3 * LOG2E); \
    LDROW(B0, t + 8,  labB); LDROW(B1, t + 9,  labA); \
    LDROW(B2, t + 10, labB); LDROW(B3, t + 11, labA); \
    u = COMB16(tree16(u, EA)) * w0; \
    u = plswap32_sum(tree16(u, EB)) * w1; \
    u = COMB16(tree16(u, EA)) * w2; \
    u = plswap32_sum(tree16(u, EB)) * w3; \
  } while (0)

    while (t + 7 <= m) {
      FBODY(P0, P1, P2, P3); t += 4;
      FBODY(Q0, Q1, Q2, Q3); t += 4;
    }
    if (t + 3 <= m) { FBODY(P0, P1, P2, P3); t += 4; }
    // drain (<=3 steps), direct loads
    while (t <= m) {
      if ((t & 3) == 1) RENORM;
      if (t & 1) {          // A-step
        float e; LDROW(e, t, labB);
        u = COMB16(tree16(u, EA)) * fexp2(e * LOG2E);
        endB = true;
      } else {              // B-step
        float e; LDROW(e, t, labA);
        u = plswap32_sum(tree16(u, EB)) * fexp2(e * LOG2E);
        endB = false;
      }
      t++;
    }
#undef FBODY
  } else {
    // ---------------- backward ----------------
    float EA[16], EB[16];
#define CBA(K) EA[K] = fexp2(Tld[labB * NL + roti<K>(labA)]);
#define CBB(K) EB[K] = fexp2(Tld[labA * NL + roti<K>(labB)]);
    CBA(0)  CBA(1)  CBA(2)  CBA(3)  CBA(4)  CBA(5)  CBA(6)  CBA(7)
    CBA(8)  CBA(9)  CBA(10) CBA(11) CBA(12) CBA(13) CBA(14) CBA(15)
    CBB(0)  CBB(1)  CBB(2)  CBB(3)  CBB(4)  CBB(5)  CBB(6)  CBB(7)
    CBB(8)  CBB(9)  CBB(10) CBB(11) CBB(12) CBB(13) CBB(14) CBB(15)
#undef CBA
#undef CBB
    float a0 = Tld[labA * NL + 30];
    ls = __int_as_float(__builtin_amdgcn_readfirstlane(__float_as_int(a0)));
    u = fexp2(a0 - ls);

#define RENORMB do { \
    const int eb_ = __builtin_amdgcn_readfirstlane(__float_as_int(u)); \
    const int ex_ = (eb_ >> 23) - 127; \
    ls += (float)ex_; \
    u *= __int_as_float((127 - ex_) << 23); \
  } while (0)

    float P0, P1, P2, P3, Q0, Q1, Q2, Q3;
    int k = 0;
    LDROW(P0, len - 1, labA); LDROW(P1, len - 2, labB);
    LDROW(P2, len - 3, labA); LDROW(P3, len - 4, labB);
    LDROW(Q0, len - 5, labA); LDROW(Q1, len - 6, labB);
    LDROW(Q2, len - 7, labA); LDROW(Q3, len - 8, labB);

#define BBODY(B0, B1, B2, B3) do { \
    RENORMB; \
    const float w0 = fexp2(B0 * LOG2E); \
    const float w1 = fexp2(B1 * LOG2E); \
    const float w2 = fexp2(B2 * LOG2E); \
    const float w3 = fexp2(B3 * LOG2E); \
    LDROW(B0, len - 1 - k - 8,  labA); LDROW(B1, len - 2 - k - 8,  labB); \
    LDROW(B2, len - 3 - k - 8,  labA); LDROW(B3, len - 4 - k - 8,  labB); \
    u = COMB16(tree16(u * w0, EA)); \
    u = plswap32_sum(tree16(u * w1, EB)); \
    u = COMB16(tree16(u * w2, EA)); \
    u = plswap32_sum(tree16(u * w3, EB)); \
  } while (0)

    while (k + 7 < nB) {
      BBODY(P0, P1, P2, P3); k += 4;
      BBODY(Q0, Q1, Q2, Q3); k += 4;
    }
    if (k + 3 < nB) { BBODY(P0, P1, P2, P3); k += 4; }
    while (k < nB) {
      if ((k & 3) == 0) RENORMB;
      if (!(k & 1)) {       // A-step
        float e; LDROW(e, len - 1 - k, labA);
        u = COMB16(tree16(u * fexp2(e * LOG2E), EA));
        endB = true;
      } else {              // B-step
        float e; LDROW(e, len - 1 - k, labB);
        u = plswap32_sum(tree16(u * fexp2(e * LOG2E), EB));
        endB = false;
      }
      k++;
    }
#undef BBODY
#undef RENORMB
  }

  // -------- junction: Z = ln2 * LSE2_j(alphalog[j] + betalog[j]) --------
  slotm[wid * 32 + (endB ? labB : labA)] = ls + flog2(u);
  __syncthreads();

  if (wid == 0) {
    float v2 = (lane < 32) ? (slotm[lane] + slotm[32 + lane]) : -3.0e38f;
    float mm = v2;
    #pragma unroll
    for (int w = 32; w; w >>= 1) mm = fmaxf(mm, __shfl_xor(mm, w));
    float ssum = fexp2(v2 - mm);
    #pragma unroll
    for (int w = 32; w; w >>= 1) ssum += __shfl_xor(ssum, w);
    if (lane == 0) atomicAdd(out + 0, LN2 * (mm + flog2(ssum)));

    // -------- labeled score --------
    const int* tb = tags + (size_t)b * NS;
    float lab = 0.0f;
    if (lane == 0) {
      const int tg0 = tb[0];
      lab += Tld[31 * NL + tg0] + LOG2E * sbf[tg0];
      const int tgl = tb[len - 1];
      lab += Tld[tgl * NL + 30];
    }
    for (int t2 = 1 + lane; t2 < len; t2 += 64) {
      const int tp = tb[t2 - 1];
      const int tg = tb[t2];
      lab += Tld[tp * NL + tg] + LOG2E * sbf[(size_t)t2 * NL + tg];
    }
    #pragma unroll
    for (int w = 32; w; w >>= 1) lab += __shfl_xor(lab, w);
    if (lane == 0) atomicAdd(out + 1, LN2 * lab);
  }
#undef COMB16
#undef LDROW
#undef RENORM
}

extern "C" void kernel_launch(void* const* d_in, const int* in_sizes, int n_in,
                              void* d_out, int out_size, void* d_ws, size_t ws_size,
                              hipStream_t stream) {
  const float* scores = (const float*)d_in[0];
  const float* trans  = (const float*)d_in[1];
  const int*   lens   = (const int*)d_in[2];
  const int*   tags   = (const int*)d_in[3];
  float* out = (float*)d_out;

  int* perm = (ws_size >= NB * sizeof(int)) ? (int*)d_ws : nullptr;

  zero_out_k<<<1, 64, 0, stream>>>(out);
  if (perm) sort_perm_k<<<1, 1024, 0, stream>>>(lens, perm);
  crf_fwd<<<NB, 128, 0, stream>>>(scores, trans, lens, tags, perm, out);
}

// Round 23
// 120.770 us; speedup vs baseline: 2.3300x; 1.0726x over previous
//
#include <hip/hip_runtime.h>

#define NB 2048
#define NS 1024
#define NL 32

static __device__ __forceinline__ float fexp2(float x) {
#if __has_builtin(__builtin_amdgcn_exp2f)
  return __builtin_amdgcn_exp2f(x);
#else
  float r; asm("v_exp_f32 %0, %1" : "=v"(r) : "v"(x)); return r;
#endif
}
static __device__ __forceinline__ float flog2(float x) {
#if __has_builtin(__builtin_amdgcn_logf)
  return __builtin_amdgcn_logf(x);
#else
  float r; asm("v_log_f32 %0, %1" : "=v"(r) : "v"(x)); return r;
#endif
}

template<int K>
static __device__ __forceinline__ int roti(int x) {
  if constexpr (K == 0) return x;
  else return __builtin_amdgcn_update_dpp(0, x, 0x120 | K, 0xf, 0xf, true); // row_ror:K
}

// part + part[pair(lane)] via permlane swaps with s_nop hazard guards (R10-validated).
static __device__ __forceinline__ float plswap16_sum(float part) {
  float x, y;
  asm volatile("v_mov_b32 %0, %2\n\t"
               "v_mov_b32 %1, %2\n\t"
               "s_nop 1\n\t"
               "v_permlane16_swap_b32 %0, %1\n\t"
               "s_nop 1"
               : "=&v"(x), "=&v"(y) : "v"(part));
  return x + y;
}
static __device__ __forceinline__ float plswap32_sum(float part) {
  float x, y;
  asm volatile("v_mov_b32 %0, %2\n\t"
               "v_mov_b32 %1, %2\n\t"
               "s_nop 1\n\t"
               "v_permlane32_swap_b32 %0, %1\n\t"
               "s_nop 1"
               : "=&v"(x), "=&v"(y) : "v"(part));
  return x + y;
}
static __device__ __forceinline__ int plswap16_partner(int lane) {
  int x, y;
  asm volatile("v_mov_b32 %0, %2\n\t"
               "v_mov_b32 %1, %2\n\t"
               "s_nop 1\n\t"
               "v_permlane16_swap_b32 %0, %1\n\t"
               "s_nop 1"
               : "=&v"(x), "=&v"(y) : "v"(lane));
  return x + y - lane;
}

// 16-term rotate/FMA tree, DPP-FUSED: each rot_k(p)*E[k] term is ONE
// v_mul/v_fmac_f32_dpp with row_ror:K on src0 — same permutation as the
// validated roti<K> (dpp_ctrl 0x120|K), so E arrival-order calibration
// carries over unchanged. Arithmetic/order identical to the unfused tree16.
// DPP hazard: only p is DPP-read; it is written >=2 VALU ops before entry,
// plus a leading s_nop 1 guard. Accumulators are plain (non-DPP) operands.
static __device__ __forceinline__ float tree16f(float p, const float* E) {
  float a0 = 0.0f, a1 = 0.0f, a2 = 0.0f, a3 = 0.0f;
  asm volatile(
    "s_nop 1\n\t"
    "v_mul_f32 %0, %4, %5\n\t"
    "v_mul_f32_dpp %1, %4, %6 row_ror:1 row_mask:0xf bank_mask:0xf\n\t"
    "v_mul_f32_dpp %2, %4, %7 row_ror:2 row_mask:0xf bank_mask:0xf\n\t"
    "v_mul_f32_dpp %3, %4, %8 row_ror:3 row_mask:0xf bank_mask:0xf\n\t"
    "v_fmac_f32_dpp %0, %4, %9 row_ror:4 row_mask:0xf bank_mask:0xf\n\t"
    "v_fmac_f32_dpp %1, %4, %10 row_ror:5 row_mask:0xf bank_mask:0xf\n\t"
    "v_fmac_f32_dpp %2, %4, %11 row_ror:6 row_mask:0xf bank_mask:0xf\n\t"
    "v_fmac_f32_dpp %3, %4, %12 row_ror:7 row_mask:0xf bank_mask:0xf\n\t"
    "v_fmac_f32_dpp %0, %4, %13 row_ror:8 row_mask:0xf bank_mask:0xf\n\t"
    "v_fmac_f32_dpp %1, %4, %14 row_ror:9 row_mask:0xf bank_mask:0xf\n\t"
    "v_fmac_f32_dpp %2, %4, %15 row_ror:10 row_mask:0xf bank_mask:0xf\n\t"
    "v_fmac_f32_dpp %3, %4, %16 row_ror:11 row_mask:0xf bank_mask:0xf\n\t"
    "v_fmac_f32_dpp %0, %4, %17 row_ror:12 row_mask:0xf bank_mask:0xf\n\t"
    "v_fmac_f32_dpp %1, %4, %18 row_ror:13 row_mask:0xf bank_mask:0xf\n\t"
    "v_fmac_f32_dpp %2, %4, %19 row_ror:14 row_mask:0xf bank_mask:0xf\n\t"
    "v_fmac_f32_dpp %3, %4, %20 row_ror:15 row_mask:0xf bank_mask:0xf"
    : "+v"(a0), "+v"(a1), "+v"(a2), "+v"(a3)
    : "v"(p),
      "v"(E[0]),  "v"(E[1]),  "v"(E[2]),  "v"(E[3]),
      "v"(E[4]),  "v"(E[5]),  "v"(E[6]),  "v"(E[7]),
      "v"(E[8]),  "v"(E[9]),  "v"(E[10]), "v"(E[11]),
      "v"(E[12]), "v"(E[13]), "v"(E[14]), "v"(E[15]));
  return (a0 + a1) + (a2 + a3);
}

__global__ void zero_out_k(float* out) {
  if (threadIdx.x < 2) out[threadIdx.x] = 0.0f;
}

// counting sort by descending length: perm[pos] = batch index, longest first.
__global__ __launch_bounds__(1024)
void sort_perm_k(const int* __restrict__ lens, int* __restrict__ perm) {
  __shared__ int h0[1024], h1[1024];
  const int tid = threadIdx.x;
  h0[tid] = 0;
  __syncthreads();
  for (int i = tid; i < NB; i += 1024) atomicAdd(&h0[1024 - lens[i]], 1);
  __syncthreads();
  const int cnt = h0[tid];
  int* src = h0; int* dst = h1;
  for (int off = 1; off < 1024; off <<= 1) {
    dst[tid] = src[tid] + ((tid >= off) ? src[tid - off] : 0);
    __syncthreads();
    int* tmp = src; src = dst; dst = tmp;
  }
  const int excl = src[tid] - cnt;
  __syncthreads();
  dst[tid] = excl;
  __syncthreads();
  for (int i = tid; i < NB; i += 1024) {
    const int key = 1024 - lens[i];
    const int pos = atomicAdd(&dst[key], 1);
    perm[pos] = i;
  }
}

// 2 waves/block: wave0 = forward alpha chain, wave1 = backward beta chain.
// Emits gathered DIRECTLY from global into an 8-deep register pipeline.
// LPT block order via perm (R22-validated). DPP-fused tree (R23).
__global__ __launch_bounds__(128, 2)
void crf_fwd(const float* __restrict__ scores, const float* __restrict__ trans,
             const int* __restrict__ lens, const int* __restrict__ tags,
             const int* __restrict__ perm, float* __restrict__ out)
{
  constexpr float LOG2E = 1.4426950408889634f;
  constexpr float LN2   = 0.6931471805599453f;
  __shared__ float Tld[NL * NL];
  __shared__ float slotm[64];

  const int b    = perm ? perm[blockIdx.x] : blockIdx.x;
  const int tid  = threadIdx.x;
  const int wid  = tid >> 6;
  const int lane = tid & 63;
  const int len  = lens[b];
  const int m    = len >> 1;            // forward: m steps -> alpha_m
  const int nB   = len - 1 - m;         // backward: nB steps -> beta_m
  const int r = lane >> 4, c = lane & 15;
  const int labA = c + ((r & 1) << 4);

  const int p16 = plswap16_partner(lane);
  const bool plOK = ((p16 & 15) == c) && ((((p16 >> 4) ^ r) & 1) == 1);
  const int pmax = (lane > p16) ? lane : p16;
  const int labB = plOK ? (c + ((pmax >= 48) ? 16 : 0))
                        : (c + (((r >> 1) & 1) << 4));

  const float* sbf = scores + (size_t)b * (NS * NL);

  for (int k2 = tid; k2 < NL * NL; k2 += 128) Tld[k2] = trans[k2] * LOG2E;
  __syncthreads();

#define COMB16(S) (plOK ? plswap16_sum(S) : ((S) + __shfl_xor((S), 16)))
// clamped global emit gather: row in [0, len-1]; one 128B line per load
#define LDROW(DST, ROW, LAB) do { \
    int r_ = (ROW); r_ = r_ < 0 ? 0 : r_; r_ = r_ > len - 1 ? len - 1 : r_; \
    DST = sbf[(size_t)r_ * NL + (LAB)]; \
  } while (0)

  float u, ls;
  bool endB = false;

  if (wid == 0) {
    // ---------------- forward ----------------
    float EA[16], EB[16];
#define CFA(K) EA[K] = fexp2(Tld[roti<K>(labA) * NL + labB]);
#define CFB(K) EB[K] = fexp2(Tld[roti<K>(labB) * NL + labA]);
    CFA(0)  CFA(1)  CFA(2)  CFA(3)  CFA(4)  CFA(5)  CFA(6)  CFA(7)
    CFA(8)  CFA(9)  CFA(10) CFA(11) CFA(12) CFA(13) CFA(14) CFA(15)
    CFB(0)  CFB(1)  CFB(2)  CFB(3)  CFB(4)  CFB(5)  CFB(6)  CFB(7)
    CFB(8)  CFB(9)  CFB(10) CFB(11) CFB(12) CFB(13) CFB(14) CFB(15)
#undef CFA
#undef CFB
    float a0 = Tld[31 * NL + labA] + LOG2E * sbf[labA];
    ls = __int_as_float(__builtin_amdgcn_readfirstlane(__float_as_int(a0)));
    u = fexp2(a0 - ls);

#define RENORM do { \
    const int eb_ = __builtin_amdgcn_readfirstlane(__float_as_int(u)); \
    const int ex_ = (eb_ >> 23) - 127; \
    ls += (float)ex_; \
    u *= __int_as_float((127 - ex_) << 23); \
  } while (0)

    // 8-deep emit pipeline: P = steps t..t+3, Q = t+4..t+7
    float P0, P1, P2, P3, Q0, Q1, Q2, Q3;
    int t = 1;
    LDROW(P0, 1, labB); LDROW(P1, 2, labA); LDROW(P2, 3, labB); LDROW(P3, 4, labA);
    LDROW(Q0, 5, labB); LDROW(Q1, 6, labA); LDROW(Q2, 7, labB); LDROW(Q3, 8, labA);

#define FBODY(B0, B1, B2, B3) do { \
    RENORM; \
    const float w0 = fexp2(B0 * LOG2E); \
    const float w1 = fexp2(B1 * LOG2E); \
    const float w2 = fexp2(B2 * LOG2E); \
    const float w3 = fexp2(B3 * LOG2E); \
    LDROW(B0, t + 8,  labB); LDROW(B1, t + 9,  labA); \
    LDROW(B2, t + 10, labB); LDROW(B3, t + 11, labA); \
    u = COMB16(tree16f(u, EA)) * w0; \
    u = plswap32_sum(tree16f(u, EB)) * w1; \
    u = COMB16(tree16f(u, EA)) * w2; \
    u = plswap32_sum(tree16f(u, EB)) * w3; \
  } while (0)

    while (t + 7 <= m) {
      FBODY(P0, P1, P2, P3); t += 4;
      FBODY(Q0, Q1, Q2, Q3); t += 4;
    }
    if (t + 3 <= m) { FBODY(P0, P1, P2, P3); t += 4; }
    // drain (<=3 steps), direct loads
    while (t <= m) {
      if ((t & 3) == 1) RENORM;
      if (t & 1) {          // A-step
        float e; LDROW(e, t, labB);
        u = COMB16(tree16f(u, EA)) * fexp2(e * LOG2E);
        endB = true;
      } else {              // B-step
        float e; LDROW(e, t, labA);
        u = plswap32_sum(tree16f(u, EB)) * fexp2(e * LOG2E);
        endB = false;
      }
      t++;
    }
#undef FBODY
  } else {
    // ---------------- backward ----------------
    float EA[16], EB[16];
#define CBA(K) EA[K] = fexp2(Tld[labB * NL + roti<K>(labA)]);
#define CBB(K) EB[K] = fexp2(Tld[labA * NL + roti<K>(labB)]);
    CBA(0)  CBA(1)  CBA(2)  CBA(3)  CBA(4)  CBA(5)  CBA(6)  CBA(7)
    CBA(8)  CBA(9)  CBA(10) CBA(11) CBA(12) CBA(13) CBA(14) CBA(15)
    CBB(0)  CBB(1)  CBB(2)  CBB(3)  CBB(4)  CBB(5)  CBB(6)  CBB(7)
    CBB(8)  CBB(9)  CBB(10) CBB(11) CBB(12) CBB(13) CBB(14) CBB(15)
#undef CBA
#undef CBB
    float a0 = Tld[labA * NL + 30];
    ls = __int_as_float(__builtin_amdgcn_readfirstlane(__float_as_int(a0)));
    u = fexp2(a0 - ls);

#define RENORMB do { \
    const int eb_ = __builtin_amdgcn_readfirstlane(__float_as_int(u)); \
    const int ex_ = (eb_ >> 23) - 127; \
    ls += (float)ex_; \
    u *= __int_as_float((127 - ex_) << 23); \
  } while (0)

    float P0, P1, P2, P3, Q0, Q1, Q2, Q3;
    int k = 0;
    LDROW(P0, len - 1, labA); LDROW(P1, len - 2, labB);
    LDROW(P2, len - 3, labA); LDROW(P3, len - 4, labB);
    LDROW(Q0, len - 5, labA); LDROW(Q1, len - 6, labB);
    LDROW(Q2, len - 7, labA); LDROW(Q3, len - 8, labB);

#define BBODY(B0, B1, B2, B3) do { \
    RENORMB; \
    const float w0 = fexp2(B0 * LOG2E); \
    const float w1 = fexp2(B1 * LOG2E); \
    const float w2 = fexp2(B2 * LOG2E); \
    const float w3 = fexp2(B3 * LOG2E); \
    LDROW(B0, len - 1 - k - 8,  labA); LDROW(B1, len - 2 - k - 8,  labB); \
    LDROW(B2, len - 3 - k - 8,  labA); LDROW(B3, len - 4 - k - 8,  labB); \
    u = COMB16(tree16f(u * w0, EA)); \
    u = plswap32_sum(tree16f(u * w1, EB)); \
    u = COMB16(tree16f(u * w2, EA)); \
    u = plswap32_sum(tree16f(u * w3, EB)); \
  } while (0)

    while (k + 7 < nB) {
      BBODY(P0, P1, P2, P3); k += 4;
      BBODY(Q0, Q1, Q2, Q3); k += 4;
    }
    if (k + 3 < nB) { BBODY(P0, P1, P2, P3); k += 4; }
    while (k < nB) {
      if ((k & 3) == 0) RENORMB;
      if (!(k & 1)) {       // A-step
        float e; LDROW(e, len - 1 - k, labA);
        u = COMB16(tree16f(u * fexp2(e * LOG2E), EA));
        endB = true;
      } else {              // B-step
        float e; LDROW(e, len - 1 - k, labB);
        u = plswap32_sum(tree16f(u * fexp2(e * LOG2E), EB));
        endB = false;
      }
      k++;
    }
#undef BBODY
#undef RENORMB
  }

  // -------- junction: Z = ln2 * LSE2_j(alphalog[j] + betalog[j]) --------
  slotm[wid * 32 + (endB ? labB : labA)] = ls + flog2(u);
  __syncthreads();

  if (wid == 0) {
    float v2 = (lane < 32) ? (slotm[lane] + slotm[32 + lane]) : -3.0e38f;
    float mm = v2;
    #pragma unroll
    for (int w = 32; w; w >>= 1) mm = fmaxf(mm, __shfl_xor(mm, w));
    float ssum = fexp2(v2 - mm);
    #pragma unroll
    for (int w = 32; w; w >>= 1) ssum += __shfl_xor(ssum, w);
    if (lane == 0) atomicAdd(out + 0, LN2 * (mm + flog2(ssum)));

    // -------- labeled score --------
    const int* tb = tags + (size_t)b * NS;
    float lab = 0.0f;
    if (lane == 0) {
      const int tg0 = tb[0];
      lab += Tld[31 * NL + tg0] + LOG2E * sbf[tg0];
      const int tgl = tb[len - 1];
      lab += Tld[tgl * NL + 30];
    }
    for (int t2 = 1 + lane; t2 < len; t2 += 64) {
      const int tp = tb[t2 - 1];
      const int tg = tb[t2];
      lab += Tld[tp * NL + tg] + LOG2E * sbf[(size_t)t2 * NL + tg];
    }
    #pragma unroll
    for (int w = 32; w; w >>= 1) lab += __shfl_xor(lab, w);
    if (lane == 0) atomicAdd(out + 1, LN2 * lab);
  }
#undef COMB16
#undef LDROW
#undef RENORM
}

extern "C" void kernel_launch(void* const* d_in, const int* in_sizes, int n_in,
                              void* d_out, int out_size, void* d_ws, size_t ws_size,
                              hipStream_t stream) {
  const float* scores = (const float*)d_in[0];
  const float* trans  = (const float*)d_in[1];
  const int*   lens   = (const int*)d_in[2];
  const int*   tags   = (const int*)d_in[3];
  float* out = (float*)d_out;

  int* perm = (ws_size >= NB * sizeof(int)) ? (int*)d_ws : nullptr;

  zero_out_k<<<1, 64, 0, stream>>>(out);
  if (perm) sort_perm_k<<<1, 1024, 0, stream>>>(lens, perm);
  crf_fwd<<<NB, 128, 0, stream>>>(scores, trans, lens, tags, perm, out);
}